// Round 1
// baseline (18037.044 us; speedup 1.0000x reference)
//
#include <hip/hip_runtime.h>
#include <hip/hip_bf16.h>
#include <math.h>

// GPT-2 forward: L=12, H=12, C=768, T=1024, V=50257, B=2, HD=64
#define TSEQ 1024
#define NBATCH 2
#define NHEAD 12
#define CDIM 768
#define NLAYER 12
#define VOCAB 50257
#define ROWS (NBATCH * TSEQ)   // 2048

typedef __attribute__((ext_vector_type(8))) short bf16x8;
typedef __attribute__((ext_vector_type(4))) float f32x4;

__device__ inline short f2bf(float f) {
    union { __hip_bfloat16 h; short s; } u;
    u.h = __float2bfloat16(f);
    return u.s;
}

// ---------------------------------------------------------------- embedding
__global__ __launch_bounds__(256) void embed_kernel(
    const int* __restrict__ idx, const float* __restrict__ tok,
    const float* __restrict__ pos, float* __restrict__ x)
{
    int row = blockIdx.x;                 // 0..2047  (b*T + t)
    int t = row & (TSEQ - 1);
    int token = idx[row];
    const float* tr = tok + (size_t)token * CDIM;
    const float* pr = pos + (size_t)t * CDIM;
    float* xr = x + (size_t)row * CDIM;
    for (int c = threadIdx.x; c < CDIM; c += 256)
        xr[c] = tr[c] + pr[c];
}

// ---------------------------------------------------------------- layernorm
// one block per row; C=768 = 3*256
__global__ __launch_bounds__(256) void ln_kernel(
    const float* __restrict__ x, const float* __restrict__ w,
    const float* __restrict__ b, __hip_bfloat16* __restrict__ out)
{
    int row = blockIdx.x;
    int tid = threadIdx.x;
    const float* xr = x + (size_t)row * CDIM;
    float v0 = xr[tid], v1 = xr[tid + 256], v2 = xr[tid + 512];
    float s = v0 + v1 + v2;
    #pragma unroll
    for (int off = 32; off; off >>= 1) s += __shfl_xor(s, off);
    __shared__ float red1[4], red2[4];
    int wave = tid >> 6;
    if ((tid & 63) == 0) red1[wave] = s;
    __syncthreads();
    float mean = (red1[0] + red1[1] + red1[2] + red1[3]) * (1.0f / CDIM);
    float d0 = v0 - mean, d1 = v1 - mean, d2 = v2 - mean;
    float sq = d0 * d0 + d1 * d1 + d2 * d2;
    #pragma unroll
    for (int off = 32; off; off >>= 1) sq += __shfl_xor(sq, off);
    if ((tid & 63) == 0) red2[wave] = sq;
    __syncthreads();
    float var = (red2[0] + red2[1] + red2[2] + red2[3]) * (1.0f / CDIM);
    float rstd = rsqrtf(var + 1e-5f);
    __hip_bfloat16* orow = out + (size_t)row * CDIM;
    orow[tid]       = __float2bfloat16(d0 * rstd * w[tid]       + b[tid]);
    orow[tid + 256] = __float2bfloat16(d1 * rstd * w[tid + 256] + b[tid + 256]);
    orow[tid + 512] = __float2bfloat16(d2 * rstd * w[tid + 512] + b[tid + 512]);
}

// ---------------------------------------------------------------- attention
// one wave per (b, h, t) query row; online softmax over keys 0..t
__global__ __launch_bounds__(64) void attn_kernel(
    const float* __restrict__ qkv, __hip_bfloat16* __restrict__ y)
{
    int id = blockIdx.x;
    int t = id & (TSEQ - 1);
    int h = (id >> 10) % NHEAD;
    int b = id / (TSEQ * NHEAD);
    int lane = threadIdx.x;
    int row = b * TSEQ + t;

    float q = qkv[(size_t)row * (3 * CDIM) + h * 64 + lane] * 0.125f; // 1/sqrt(64)
    const float* kbase = qkv + (size_t)b * TSEQ * (3 * CDIM) + CDIM + h * 64 + lane;
    const float* vbase = kbase + CDIM;

    float m = -INFINITY, l = 0.f, acc = 0.f;
    for (int j = 0; j <= t; ++j) {
        float kj = kbase[(size_t)j * (3 * CDIM)];
        float vj = vbase[(size_t)j * (3 * CDIM)];
        float s = q * kj;
        #pragma unroll
        for (int off = 32; off; off >>= 1) s += __shfl_xor(s, off);
        float mnew = fmaxf(m, s);
        float f = __expf(m - mnew);     // first iter: exp(-inf)=0
        float p = __expf(s - mnew);
        l = l * f + p;
        acc = acc * f + p * vj;
        m = mnew;
    }
    y[(size_t)row * CDIM + h * 64 + lane] = __float2bfloat16(acc / l);
}

// ---------------------------------------------------------------- GEMM
// C[m,n] = sum_k A[m,k] * B'[k,n]  (+bias, +residual, gelu, bf16-out options)
// A: bf16 [M,K] row-major.
// NT=true : B is f32 [N,K] (row-major, K contiguous)  -> direct staging
// NT=false: B is f32 [K,N] (row-major, N contiguous)  -> transposing staging
// Tile 128x128xBK32, 4 waves, each wave a 64x64 subtile of 4x4 MFMA 16x16x32.
template <bool NT, bool BIAS, bool RES, bool GELU, bool OUTBF>
__global__ __launch_bounds__(256) void gemm_kernel(
    const __hip_bfloat16* __restrict__ A,
    const float* __restrict__ B,
    const float* __restrict__ bias,
    const float* __restrict__ resid,
    float* __restrict__ Cf,
    __hip_bfloat16* __restrict__ Cb,
    int M, int N, int K)
{
    constexpr int BSTR = NT ? 32 : 40;  // pad NN B-tile rows to dodge worst conflicts
    __shared__ __align__(16) short As[128][32];
    __shared__ __align__(16) short Bs[128][BSTR];

    const int tid = threadIdx.x;
    const int lane = tid & 63;
    const int wave = tid >> 6;
    const int wm = (wave >> 1) * 64;
    const int wn = (wave & 1) * 64;
    const int l15 = lane & 15;
    const int quad = lane >> 4;
    const int bn0 = blockIdx.x * 128;
    const int bm0 = blockIdx.y * 128;

    f32x4 acc[4][4] = {};

    for (int k0 = 0; k0 < K; k0 += 32) {
        // ---- stage A tile [128][32] (bf16, direct 16B copies)
        #pragma unroll
        for (int it = 0; it < 2; ++it) {
            int flat = it * 256 + tid;
            int r = flat >> 2;
            int kk = (flat & 3) << 3;
            bf16x8 v = *(const bf16x8*)(A + (size_t)(bm0 + r) * K + k0 + kk);
            *(bf16x8*)&As[r][kk] = v;
        }
        // ---- stage B tile -> Bs[n][k] (bf16)
        if constexpr (NT) {
            #pragma unroll
            for (int it = 0; it < 4; ++it) {
                int flat = it * 256 + tid;
                int n = flat >> 3;
                int kq = (flat & 7) << 2;
                int gn = bn0 + n;
                float4 bv;
                if (gn < N) bv = *(const float4*)(B + (size_t)gn * K + k0 + kq);
                else        bv = make_float4(0.f, 0.f, 0.f, 0.f);
                short4 sv;
                sv.x = f2bf(bv.x); sv.y = f2bf(bv.y);
                sv.z = f2bf(bv.z); sv.w = f2bf(bv.w);
                *(short4*)&Bs[n][kq] = sv;
            }
        } else {
            #pragma unroll
            for (int it = 0; it < 4; ++it) {
                int flat = it * 256 + tid;
                int kr = flat >> 5;             // 0..31
                int n4 = (flat & 31) << 2;      // 0..124
                float4 bv = *(const float4*)(B + (size_t)(k0 + kr) * N + bn0 + n4);
                Bs[n4 + 0][kr] = f2bf(bv.x);
                Bs[n4 + 1][kr] = f2bf(bv.y);
                Bs[n4 + 2][kr] = f2bf(bv.z);
                Bs[n4 + 3][kr] = f2bf(bv.w);
            }
        }
        __syncthreads();

        // ---- fragments + MFMA
        bf16x8 af[4], bfr[4];
        #pragma unroll
        for (int i = 0; i < 4; ++i)
            af[i] = *(const bf16x8*)&As[wm + i * 16 + l15][quad * 8];
        #pragma unroll
        for (int j = 0; j < 4; ++j)
            bfr[j] = *(const bf16x8*)&Bs[wn + j * 16 + l15][quad * 8];
        #pragma unroll
        for (int i = 0; i < 4; ++i)
            #pragma unroll
            for (int j = 0; j < 4; ++j)
                acc[i][j] = __builtin_amdgcn_mfma_f32_16x16x32_bf16(
                    af[i], bfr[j], acc[i][j], 0, 0, 0);
        __syncthreads();
    }

    // ---- epilogue: D row = quad*4 + r, col = l15  (verified m89/m91 mapping)
    #pragma unroll
    for (int i = 0; i < 4; ++i) {
        #pragma unroll
        for (int j = 0; j < 4; ++j) {
            #pragma unroll
            for (int r = 0; r < 4; ++r) {
                int row = bm0 + wm + i * 16 + quad * 4 + r;
                int col = bn0 + wn + j * 16 + l15;
                if (col < N) {
                    float v = acc[i][j][r];
                    if (BIAS) v += bias[col];
                    if (GELU) v = 0.5f * v * (1.0f + erff(v * 0.70710678118f));
                    if (RES)  v += resid[(size_t)row * N + col];
                    if (OUTBF) Cb[(size_t)row * N + col] = __float2bfloat16(v);
                    else       Cf[(size_t)row * N + col] = v;
                }
            }
        }
    }
}

// ---------------------------------------------------------------- launch
extern "C" void kernel_launch(void* const* d_in, const int* in_sizes, int n_in,
                              void* d_out, int out_size, void* d_ws, size_t ws_size,
                              hipStream_t stream)
{
    (void)in_sizes; (void)n_in; (void)out_size; (void)ws_size;

    const int*   idx     = (const int*)d_in[0];
    const float* tok_emb = (const float*)d_in[1];
    const float* pos_emb = (const float*)d_in[2];
    const float* ln1_w   = (const float*)d_in[3];
    const float* ln1_b   = (const float*)d_in[4];
    const float* w_qkv   = (const float*)d_in[5];
    const float* b_qkv   = (const float*)d_in[6];
    const float* w_proj  = (const float*)d_in[7];
    const float* b_proj  = (const float*)d_in[8];
    const float* ln2_w   = (const float*)d_in[9];
    const float* ln2_b   = (const float*)d_in[10];
    const float* w_fc    = (const float*)d_in[11];
    const float* b_fc    = (const float*)d_in[12];
    const float* w_fc2   = (const float*)d_in[13];
    const float* b_fc2   = (const float*)d_in[14];
    const float* lnf_w   = (const float*)d_in[15];
    const float* lnf_b   = (const float*)d_in[16];

    // workspace layout (~44 MB)
    float* x   = (float*)d_ws;                       // [2048, 768]  f32
    float* qkv = x + (size_t)ROWS * CDIM;            // [2048, 2304] f32
    __hip_bfloat16* hbuf = (__hip_bfloat16*)(qkv + (size_t)ROWS * 3 * CDIM); // [2048,768]
    __hip_bfloat16* ybuf = hbuf + (size_t)ROWS * CDIM;                       // [2048,768]
    __hip_bfloat16* ffn  = ybuf + (size_t)ROWS * CDIM;                       // [2048,3072]

    embed_kernel<<<ROWS, 256, 0, stream>>>(idx, tok_emb, pos_emb, x);

    dim3 g_qkv(3 * CDIM / 128, ROWS / 128);
    dim3 g_proj(CDIM / 128, ROWS / 128);
    dim3 g_fc(4 * CDIM / 128, ROWS / 128);
    dim3 g_head((VOCAB + 127) / 128, ROWS / 128);

    for (int l = 0; l < NLAYER; ++l) {
        const float* l1w = ln1_w + l * CDIM;
        const float* l1b = ln1_b + l * CDIM;
        const float* l2w = ln2_w + l * CDIM;
        const float* l2b = ln2_b + l * CDIM;
        const float* wqkv_l = w_qkv + (size_t)l * CDIM * 3 * CDIM;
        const float* bqkv_l = b_qkv + (size_t)l * 3 * CDIM;
        const float* wpr_l  = w_proj + (size_t)l * CDIM * CDIM;
        const float* bpr_l  = b_proj + (size_t)l * CDIM;
        const float* wfc_l  = w_fc + (size_t)l * CDIM * 4 * CDIM;
        const float* bfc_l  = b_fc + (size_t)l * 4 * CDIM;
        const float* wf2_l  = w_fc2 + (size_t)l * 4 * CDIM * CDIM;
        const float* bf2_l  = b_fc2 + (size_t)l * CDIM;

        ln_kernel<<<ROWS, 256, 0, stream>>>(x, l1w, l1b, hbuf);
        gemm_kernel<false, true, false, false, false><<<g_qkv, 256, 0, stream>>>(
            hbuf, wqkv_l, bqkv_l, nullptr, qkv, nullptr, ROWS, 3 * CDIM, CDIM);
        attn_kernel<<<NBATCH * NHEAD * TSEQ, 64, 0, stream>>>(qkv, ybuf);
        gemm_kernel<false, true, true, false, false><<<g_proj, 256, 0, stream>>>(
            ybuf, wpr_l, bpr_l, x, x, nullptr, ROWS, CDIM, CDIM);
        ln_kernel<<<ROWS, 256, 0, stream>>>(x, l2w, l2b, hbuf);
        gemm_kernel<false, true, false, true, true><<<g_fc, 256, 0, stream>>>(
            hbuf, wfc_l, bfc_l, nullptr, nullptr, ffn, ROWS, 4 * CDIM, CDIM);
        gemm_kernel<false, true, true, false, false><<<g_proj, 256, 0, stream>>>(
            ffn, wf2_l, bf2_l, x, x, nullptr, ROWS, CDIM, 4 * CDIM);
    }

    ln_kernel<<<ROWS, 256, 0, stream>>>(x, lnf_w, lnf_b, hbuf);
    gemm_kernel<true, false, false, false, false><<<g_head, 256, 0, stream>>>(
        hbuf, tok_emb, nullptr, nullptr, (float*)d_out, nullptr, ROWS, VOCAB, CDIM);
}